// Round 7
// baseline (74.804 us; speedup 1.0000x reference)
//
#include <hip/hip_runtime.h>
#include <hip/hip_bf16.h>

// Poincare pairwise distance, c=1:
//   d(x,p) = acosh(1 + 2*||x-p||^2 / ((1-||x||^2)(1-||p||^2)))
// B=16384, N=4096, D=64. Output 16384x4096 f32 (256 MiB) -> write-bound.
//
// Round 7: ZERO-LDS, ZERO-BARRIER main kernel. The prepass writes emb/proto
// to ws in MFMA *fragment order* (16B per lane, lane-consecutive), so each
// wave loads its fragments directly from global memory as fully-coalesced
// 1KB global_load_dwordx4 (L2-hot: proto ws = 512 KB < 4 MiB per-XCD L2).
// Waves are completely independent: loads/MFMA/epilogue/stores of the
// ~16 resident waves per CU interleave freely -> continuous store issue.
//
// Fragment layouts in ws (16B chunks):
//   emb:   chunk((strip,kk,lane))  = strip*128 + kk*64 + lane
//          content = bf16 emb[strip*16 + (lane&15)][kk*32+(lane>>4)*8 .. +7]
//   proto: chunk((nt,pf,kk,lane)) = nt*1024 + (pf*2+kk)*64 + lane
//          content = bf16 proto[nt*128 + pf*16 + (lane&15)][kk*32+(lane>>4)*8 .. +7]

constexpr int BATCH = 16384;
constexpr int NCON  = 4096;
constexpr int DIM   = 64;
constexpr float LN2 = 0.6931471805599453f;

// ws layout (bytes), 16B-aligned:
constexpr size_t WS_EMB   = 0;                        // 1024 strips * 2KiB = 2 MiB
constexpr size_t WS_PROTO = (size_t)2 << 20;          // 32 tiles * 16KiB = 512 KiB
constexpr size_t WS_X2    = WS_PROTO + (512u << 10);  // f32[16384]
constexpr size_t WS_CROW  = WS_X2   + 64u * 1024;     // f32[16384]
constexpr size_t WS_P2    = WS_CROW + 64u * 1024;     // f32[4096]
constexpr size_t WS_RP    = WS_P2   + 16u * 1024;     // f32[4096]

typedef float  f32x4  __attribute__((ext_vector_type(4)));
typedef __bf16 bf16x8 __attribute__((ext_vector_type(8)));

// ---------------- pre-pass ----------------
// gid sections: [0,131072) emb fragment chunks, [131072,163840) proto chunks,
//               [163840,180224) emb norms, [180224,184320) proto norms.
__global__ __launch_bounds__(256)
void prepass_kernel(const float* __restrict__ emb,
                    const float* __restrict__ proto,
                    char* __restrict__ ws)
{
    int gid = blockIdx.x * 256 + threadIdx.x;
    if (gid < 131072) {
        int c = gid;
        int strip = c >> 7, r = c & 127;
        int kk = r >> 6, lane = r & 63;
        int row = strip * 16 + (lane & 15);
        int k0  = kk * 32 + (lane >> 4) * 8;
        const float* src = emb + (size_t)row * DIM + k0;
        f32x4 a = *reinterpret_cast<const f32x4*>(src);
        f32x4 b = *reinterpret_cast<const f32x4*>(src + 4);
        bf16x8 v;
        v[0]=(__bf16)a.x; v[1]=(__bf16)a.y; v[2]=(__bf16)a.z; v[3]=(__bf16)a.w;
        v[4]=(__bf16)b.x; v[5]=(__bf16)b.y; v[6]=(__bf16)b.z; v[7]=(__bf16)b.w;
        *reinterpret_cast<bf16x8*>(ws + WS_EMB + (size_t)c * 16) = v;
    } else if (gid < 163840) {
        int c = gid - 131072;
        int nt = c >> 10, r = c & 1023;
        int pf = r >> 7, rr = r & 127;
        int kk = rr >> 6, lane = rr & 63;
        int row = nt * 128 + pf * 16 + (lane & 15);
        int k0  = kk * 32 + (lane >> 4) * 8;
        const float* src = proto + (size_t)row * DIM + k0;
        f32x4 a = *reinterpret_cast<const f32x4*>(src);
        f32x4 b = *reinterpret_cast<const f32x4*>(src + 4);
        bf16x8 v;
        v[0]=(__bf16)a.x; v[1]=(__bf16)a.y; v[2]=(__bf16)a.z; v[3]=(__bf16)a.w;
        v[4]=(__bf16)b.x; v[5]=(__bf16)b.y; v[6]=(__bf16)b.z; v[7]=(__bf16)b.w;
        *reinterpret_cast<bf16x8*>(ws + WS_PROTO + (size_t)c * 16) = v;
    } else if (gid < 180224) {
        int r = gid - 163840;
        const f32x4* src = reinterpret_cast<const f32x4*>(emb + (size_t)r * DIM);
        float s = 0.0f;
        #pragma unroll
        for (int i = 0; i < 16; ++i) {
            f32x4 v = src[i];
            s += v.x*v.x + v.y*v.y + v.z*v.z + v.w*v.w;
        }
        reinterpret_cast<float*>(ws + WS_X2)[r]   = s;
        reinterpret_cast<float*>(ws + WS_CROW)[r] = 2.0f * __builtin_amdgcn_rcpf(1.0f - s);
    } else if (gid < 184320) {
        int r = gid - 180224;
        const f32x4* src = reinterpret_cast<const f32x4*>(proto + (size_t)r * DIM);
        float s = 0.0f;
        #pragma unroll
        for (int i = 0; i < 16; ++i) {
            f32x4 v = src[i];
            s += v.x*v.x + v.y*v.y + v.z*v.z + v.w*v.w;
        }
        reinterpret_cast<float*>(ws + WS_P2)[r] = s;
        reinterpret_cast<float*>(ws + WS_RP)[r] = __builtin_amdgcn_rcpf(1.0f - s);
    }
}

// ---------------- main kernel: no LDS, no barriers ----------------
// Block = 4 waves; wave w owns emb strip (mg*4 + w) = 16 rows, and the block's
// 2 proto tiles (256 protos). Grid = 256 m-groups * 16 n-groups = 4096.
__global__ __launch_bounds__(256, 4)
void poincare_pairwise_kernel(const char* __restrict__ ws,
                              float* __restrict__ out)
{
    const int tid  = threadIdx.x;
    const int bid  = blockIdx.x;
    const int mg   = bid >> 4;         // 0..255
    const int ng   = bid & 15;         // 0..15
    const int lane = tid & 63;
    const int wid  = tid >> 6;
    const int lr   = lane & 15;
    const int g    = lane >> 4;
    const int strip = mg * 4 + wid;
    const int row   = strip * 16 + lr;

    // emb fragments: 2 coalesced 16B/lane loads
    const bf16x8* ebase = reinterpret_cast<const bf16x8*>(ws + WS_EMB) + (size_t)strip * 128 + lane;
    const bf16x8 xfrag0 = ebase[0];
    const bf16x8 xfrag1 = ebase[64];

    const float x2   = reinterpret_cast<const float*>(ws + WS_X2)[row];
    const float crow = reinterpret_cast<const float*>(ws + WS_CROW)[row];
    float* rowp = out + (size_t)row * NCON;

    #pragma unroll
    for (int t = 0; t < 2; ++t) {
        const int nt = ng * 2 + t;
        const bf16x8* pbase = reinterpret_cast<const bf16x8*>(ws + WS_PROTO) + (size_t)nt * 1024 + lane;

        f32x4 acc[8] = {};
        #pragma unroll
        for (int kk = 0; kk < 2; ++kk) {
            bf16x8 pfrag[8];
            #pragma unroll
            for (int pf = 0; pf < 8; ++pf)
                pfrag[pf] = pbase[(pf * 2 + kk) * 64];
            #pragma unroll
            for (int pf = 0; pf < 8; ++pf)
                acc[pf] = __builtin_amdgcn_mfma_f32_16x16x32_bf16(
                    pfrag[pf], kk ? xfrag1 : xfrag0, acc[pf], 0, 0, 0);
        }

        // epilogue: D layout col=lane&15 -> emb row (lr); row=g*4+j -> proto.
        // 4 lanes {lr, lr+16, lr+32, lr+48} write one contiguous 64B line.
        const float* p2a = reinterpret_cast<const float*>(ws + WS_P2) + nt * 128;
        const float* rpa = reinterpret_cast<const float*>(ws + WS_RP) + nt * 128;
        #pragma unroll
        for (int pf = 0; pf < 8; ++pf) {
            int   col = pf * 16 + g * 4;
            f32x4 p2  = *reinterpret_cast<const f32x4*>(p2a + col);
            f32x4 rp  = *reinterpret_cast<const f32x4*>(rpa + col);
            f32x4 dv;
            #pragma unroll
            for (int j = 0; j < 4; ++j) {
                float sq = fmaxf(x2 + p2[j] - 2.0f * acc[pf][j], 0.0f);
                float tt = sq * (crow * rp[j]);
                float s  = __builtin_amdgcn_sqrtf(tt * (tt + 2.0f));
                dv[j]    = LN2 * __builtin_amdgcn_logf(1.0f + tt + s);
            }
            *reinterpret_cast<f32x4*>(rowp + nt * 128 + col) = dv;
        }
    }
}

extern "C" void kernel_launch(void* const* d_in, const int* in_sizes, int n_in,
                              void* d_out, int out_size, void* d_ws, size_t ws_size,
                              hipStream_t stream) {
    const float* emb   = (const float*)d_in[0];
    const float* proto = (const float*)d_in[1];
    float* out = (float*)d_out;
    char* ws   = (char*)d_ws;

    prepass_kernel<<<720, 256, 0, stream>>>(emb, proto, ws);   // 184320 threads
    poincare_pairwise_kernel<<<4096, 256, 0, stream>>>(ws, out);
}

// Round 8
// 61.148 us; speedup vs baseline: 1.2233x; 1.2233x over previous
//
#include <hip/hip_runtime.h>
#include <hip/hip_bf16.h>

// Poincare pairwise distance, c=1:
//   d(x,p) = acosh(1 + 2*||x-p||^2 / ((1-||x||^2)(1-||p||^2)))
// B=16384, N=4096, D=64. Output 16384x4096 f32 (256 MiB) -> write-bound.
//
// Round 8: R6 skeleton (prepass -> pre-swizzled bf16 tile images; pure-copy
// staging; one barrier; barrier-free epilogue) + READ-TRAFFIC reduction:
//   - 128x128 tile (reads/block: 32KB, 4096 blocks -> 128MB pre-L2)
//   - XCD-aware swizzle: xcd=bid&7 owns a 2048-row emb band; within an XCD
//     16 consecutive blocks share one proto tile while cycling a 256KB emb
//     band -> per-XCD L2 working set ~300KB survives the write-stream
//     thrash -> ws reads hit L2, HBM reads ~compulsory only.

constexpr int BATCH = 16384;
constexpr int NCON  = 4096;
constexpr int DIM   = 64;
constexpr int TM    = 128;
constexpr int TN    = 128;
constexpr float LN2 = 0.6931471805599453f;

// ws layout (bytes), 16B-aligned (identical bytes to round 6):
constexpr size_t WS_EMB   = 0;                        // 2 MiB  (bf16 swizzled emb images)
constexpr size_t WS_PROTO = (size_t)2 << 20;          // 512 KiB (bf16 swizzled proto images)
constexpr size_t WS_X2    = WS_PROTO + (512u << 10);  // f32[16384]
constexpr size_t WS_CROW  = WS_X2   + 64u * 1024;     // f32[16384]
constexpr size_t WS_P2    = WS_CROW + 64u * 1024;     // f32[4096]
constexpr size_t WS_RP    = WS_P2   + 16u * 1024;     // f32[4096]

typedef float  f32x4  __attribute__((ext_vector_type(4)));
typedef __bf16 bf16x8 __attribute__((ext_vector_type(8)));

// ---------------- pre-pass (unchanged from round 6) ----------------
__global__ __launch_bounds__(256)
void prepass_kernel(const float* __restrict__ emb,
                    const float* __restrict__ proto,
                    char* __restrict__ ws)
{
    int gid = blockIdx.x * 256 + threadIdx.x;
    if (gid < 131072) {
        // emb bf16 swizzled row images: 16B chunk c covers 8 elements.
        int c = gid;
        int mt = c >> 9, within = c & 511;          // 64-row half-tiles
        int e0  = within * 8;
        int row = e0 >> 6;
        int k0  = (e0 & 63) ^ ((row & 7) << 3);
        const float* src = emb + (size_t)(mt * 64 + row) * DIM + k0;
        f32x4 a = *reinterpret_cast<const f32x4*>(src);
        f32x4 b = *reinterpret_cast<const f32x4*>(src + 4);
        bf16x8 v;
        v[0]=(__bf16)a.x; v[1]=(__bf16)a.y; v[2]=(__bf16)a.z; v[3]=(__bf16)a.w;
        v[4]=(__bf16)b.x; v[5]=(__bf16)b.y; v[6]=(__bf16)b.z; v[7]=(__bf16)b.w;
        *reinterpret_cast<bf16x8*>(ws + WS_EMB + (size_t)c * 16) = v;
    } else if (gid < 163840) {
        int c = gid - 131072;
        int nt = c >> 10, within = c & 1023;        // 128-row tiles
        int e0  = within * 8;
        int row = e0 >> 6;
        int k0  = (e0 & 63) ^ ((row & 7) << 3);
        const float* src = proto + (size_t)(nt * 128 + row) * DIM + k0;
        f32x4 a = *reinterpret_cast<const f32x4*>(src);
        f32x4 b = *reinterpret_cast<const f32x4*>(src + 4);
        bf16x8 v;
        v[0]=(__bf16)a.x; v[1]=(__bf16)a.y; v[2]=(__bf16)a.z; v[3]=(__bf16)a.w;
        v[4]=(__bf16)b.x; v[5]=(__bf16)b.y; v[6]=(__bf16)b.z; v[7]=(__bf16)b.w;
        *reinterpret_cast<bf16x8*>(ws + WS_PROTO + (size_t)c * 16) = v;
    } else if (gid < 180224) {
        int r = gid - 163840;
        const f32x4* src = reinterpret_cast<const f32x4*>(emb + (size_t)r * DIM);
        float s = 0.0f;
        #pragma unroll
        for (int i = 0; i < 16; ++i) {
            f32x4 v = src[i];
            s += v.x*v.x + v.y*v.y + v.z*v.z + v.w*v.w;
        }
        reinterpret_cast<float*>(ws + WS_X2)[r]   = s;
        reinterpret_cast<float*>(ws + WS_CROW)[r] = 2.0f * __builtin_amdgcn_rcpf(1.0f - s);
    } else if (gid < 184320) {
        int r = gid - 180224;
        const f32x4* src = reinterpret_cast<const f32x4*>(proto + (size_t)r * DIM);
        float s = 0.0f;
        #pragma unroll
        for (int i = 0; i < 16; ++i) {
            f32x4 v = src[i];
            s += v.x*v.x + v.y*v.y + v.z*v.z + v.w*v.w;
        }
        reinterpret_cast<float*>(ws + WS_P2)[r] = s;
        reinterpret_cast<float*>(ws + WS_RP)[r] = __builtin_amdgcn_rcpf(1.0f - s);
    }
}

// ---------------- main kernel ----------------
// 4 waves; wave owns 32 emb rows x 128 protos. 3 blocks/CU.
__global__ __launch_bounds__(256, 3)
void poincare_pairwise_kernel(const char* __restrict__ ws,
                              float* __restrict__ out)
{
    __shared__ __bf16 As[TM * DIM];   // 16 KiB (pre-swizzled image)
    __shared__ __bf16 Bs[TN * DIM];   // 16 KiB

    const int tid = threadIdx.x;
    const int bid = blockIdx.x;
    // XCD-aware mapping: xcd owns emb band of 16 m-tiles; n-outer, m-inner.
    const int xcd = bid & 7;
    const int q   = bid >> 3;          // 0..511
    const int mt  = xcd * 16 + (q & 15);
    const int nt  = q >> 4;            // 0..31
    const int m0  = mt * TM;
    const int n0  = nt * TN;

    // ---------- staging: pure linear uint4 copy ----------
    {
        const uint4* esrc = reinterpret_cast<const uint4*>(ws + WS_EMB + (size_t)mt * 16384);
        uint4* edst = reinterpret_cast<uint4*>(As);
        const uint4* psrc = reinterpret_cast<const uint4*>(ws + WS_PROTO + (size_t)nt * 16384);
        uint4* pdst = reinterpret_cast<uint4*>(Bs);
        #pragma unroll
        for (int i = 0; i < 4; ++i) {
            edst[i * 256 + tid] = esrc[i * 256 + tid];
            pdst[i * 256 + tid] = psrc[i * 256 + tid];
        }
    }

    const int lane = tid & 63;
    const int wid  = tid >> 6;         // wave -> 32-row emb strip
    const int lr   = lane & 15;
    const int g    = lane >> 4;
    const int lk   = g * 8;

    // per-lane row params (issued while staging is in flight)
    float  x2[2], crow[2];
    float* rowp[2];
    #pragma unroll
    for (int rf = 0; rf < 2; ++rf) {
        int xrow = wid * 32 + rf * 16 + lr;
        x2[rf]   = reinterpret_cast<const float*>(ws + WS_X2)[m0 + xrow];
        crow[rf] = reinterpret_cast<const float*>(ws + WS_CROW)[m0 + xrow];
        rowp[rf] = out + (size_t)(m0 + xrow) * NCON + n0;
    }

    __syncthreads();   // the ONLY barrier

    // ---------- MFMA: wave = 32 emb rows x 128 protos ----------
    bf16x8 xfrag[2][2];                // [rf][kk]
    #pragma unroll
    for (int rf = 0; rf < 2; ++rf) {
        int xrow = wid * 32 + rf * 16 + lr;
        #pragma unroll
        for (int kk = 0; kk < 2; ++kk) {
            int ke = (kk * 32 + lk) ^ ((xrow & 7) << 3);
            xfrag[rf][kk] = *reinterpret_cast<const bf16x8*>(&As[xrow * DIM + ke]);
        }
    }
    f32x4 acc[2][8] = {};              // [rf][pf]
    #pragma unroll
    for (int kk = 0; kk < 2; ++kk) {
        bf16x8 pfrag[8];
        #pragma unroll
        for (int pf = 0; pf < 8; ++pf) {
            int prow = pf * 16 + lr;
            int kep  = (kk * 32 + lk) ^ ((prow & 7) << 3);
            pfrag[pf] = *reinterpret_cast<const bf16x8*>(&Bs[prow * DIM + kep]);
        }
        #pragma unroll
        for (int pf = 0; pf < 8; ++pf) {
            acc[0][pf] = __builtin_amdgcn_mfma_f32_16x16x32_bf16(pfrag[pf], xfrag[0][kk], acc[0][pf], 0, 0, 0);
            acc[1][pf] = __builtin_amdgcn_mfma_f32_16x16x32_bf16(pfrag[pf], xfrag[1][kk], acc[1][pf], 0, 0, 0);
        }
    }

    // ---------- epilogue: distance + store (no barriers) ----------
    // D layout: col = lane&15 -> emb row (lr); row = g*4+j -> proto idx.
    const float* p2a = reinterpret_cast<const float*>(ws + WS_P2) + n0;
    const float* rpa = reinterpret_cast<const float*>(ws + WS_RP) + n0;
    #pragma unroll
    for (int pf = 0; pf < 8; ++pf) {
        int   col = pf * 16 + g * 4;
        f32x4 p2  = *reinterpret_cast<const f32x4*>(p2a + col);
        f32x4 rp  = *reinterpret_cast<const f32x4*>(rpa + col);
        #pragma unroll
        for (int rf = 0; rf < 2; ++rf) {
            f32x4 dv;
            #pragma unroll
            for (int j = 0; j < 4; ++j) {
                float sq = fmaxf(x2[rf] + p2[j] - 2.0f * acc[rf][pf][j], 0.0f);
                float tt = sq * (crow[rf] * rp[j]);
                float s  = __builtin_amdgcn_sqrtf(tt * (tt + 2.0f));
                dv[j]    = LN2 * __builtin_amdgcn_logf(1.0f + tt + s);
            }
            *reinterpret_cast<f32x4*>(rowp[rf] + col) = dv;
        }
    }
}

extern "C" void kernel_launch(void* const* d_in, const int* in_sizes, int n_in,
                              void* d_out, int out_size, void* d_ws, size_t ws_size,
                              hipStream_t stream) {
    const float* emb   = (const float*)d_in[0];
    const float* proto = (const float*)d_in[1];
    float* out = (float*)d_out;
    char* ws   = (char*)d_ws;

    prepass_kernel<<<720, 256, 0, stream>>>(emb, proto, ws);   // 184320 threads
    poincare_pairwise_kernel<<<4096, 256, 0, stream>>>(ws, out);
}